// Round 6
// baseline (203.838 us; speedup 1.0000x reference)
//
#include <hip/hip_runtime.h>
#include <stdint.h>

using u16 = unsigned short;
typedef __attribute__((ext_vector_type(8))) _Float16 half8;
typedef __attribute__((ext_vector_type(4))) float f32x4;
typedef __attribute__((ext_vector_type(4))) unsigned short u16x4;

#define S_LEN 2048
#define D_MODEL 1024
#define NHEAD 16
#define HDIM 64

__device__ __forceinline__ u16 f2h_bits(float f){
    _Float16 h = (_Float16)f;
    return __builtin_bit_cast(u16, h);
}

typedef __attribute__((address_space(1))) void gvoid;
typedef __attribute__((address_space(3))) void lvoid;
__device__ __forceinline__ void gload_lds16(const u16* g, u16* l){
    __builtin_amdgcn_global_load_lds((gvoid*)(uintptr_t)g, (lvoid*)l, 16, 0, 0);
}

// ---------- x fp32 -> fp16 ----------
__global__ __launch_bounds__(256) void k_cvt_x(const float* __restrict__ x, u16* __restrict__ xh){
    int i = blockIdx.x*256 + threadIdx.x;
    float4 v = reinterpret_cast<const float4*>(x)[i];
    u16x4 o;
    o.x = f2h_bits(v.x); o.y = f2h_bits(v.y); o.z = f2h_bits(v.z); o.w = f2h_bits(v.w);
    reinterpret_cast<u16x4*>(xh)[i] = o;
}

// ---------- W [K][N] fp32 -> WT [N][K] fp16 (transpose via LDS) ----------
__global__ __launch_bounds__(256) void k_cvt_wT(const float* __restrict__ W, u16* __restrict__ WT,
                                                int K, int N){
    __shared__ float t[32][33];
    int tx = threadIdx.x & 31, ty = threadIdx.x >> 5;   // 32 x 8
    int n0 = blockIdx.x*32, k0 = blockIdx.y*32;
    #pragma unroll
    for (int i=0;i<4;++i) t[ty+8*i][tx] = W[(size_t)(k0+ty+8*i)*N + n0+tx];
    __syncthreads();
    #pragma unroll
    for (int i=0;i<4;++i) WT[(size_t)(n0+ty+8*i)*K + k0+tx] = f2h_bits(t[tx][ty+8*i]);
}

// ---------- GEMM (m97 structure): 128x128 tile, BK=32, LDS-staged via global_load_lds ----------
template<int EPI>
__global__ __launch_bounds__(256) void k_gemm(const u16* __restrict__ A, const u16* __restrict__ BT,
                                              float* __restrict__ Cf, u16* __restrict__ Qh,
                                              u16* __restrict__ Kh, u16* __restrict__ Vt){
    constexpr int Kd = 1024;
    __shared__ u16 As[128*32];
    __shared__ u16 Bs[128*32];
    int nwg = gridDim.x;
    int cpx = nwg >> 3;
    int wg  = ((int)blockIdx.x & 7)*cpx + ((int)blockIdx.x >> 3);   // XCD-chunked
    int tm = wg & 31, tn = wg >> 5;                                 // m-fastest within chunk
    int t = threadIdx.x;
    int w = t >> 6, lane = t & 63;
    int lr = lane & 15, lg = lane >> 4;
    int wm = (w>>1)*64, wn = (w&1)*64;
    int m0 = tm*128 + wm, n0 = tn*128 + wn;

    const u16* aG = A  + (size_t)(tm*128 + (t>>2))*Kd + (t&3)*8;
    const u16* bG = BT + (size_t)(tn*128 + (t>>2))*Kd + (t&3)*8;
    u16* aL = As + (t>>2)*32 + (t&3)*8;
    u16* bL = Bs + (t>>2)*32 + (t&3)*8;

    f32x4 acc[4][4];
    #pragma unroll
    for (int i=0;i<4;++i)
        #pragma unroll
        for (int j=0;j<4;++j) acc[i][j] = (f32x4){0.f,0.f,0.f,0.f};

    for (int kk=0; kk<Kd; kk+=32){
        gload_lds16(aG + kk, aL);
        gload_lds16(aG + kk + (size_t)64*Kd, aL + 64*32);
        gload_lds16(bG + kk, bL);
        gload_lds16(bG + kk + (size_t)64*Kd, bL + 64*32);
        __syncthreads();

        half8 av[4], bv[4];
        #pragma unroll
        for (int mf=0;mf<4;++mf) av[mf] = *reinterpret_cast<const half8*>(&As[(wm+mf*16+lr)*32 + lg*8]);
        #pragma unroll
        for (int nf=0;nf<4;++nf) bv[nf] = *reinterpret_cast<const half8*>(&Bs[(wn+nf*16+lr)*32 + lg*8]);
        __builtin_amdgcn_s_setprio(1);
        #pragma unroll
        for (int mf=0;mf<4;++mf)
            #pragma unroll
            for (int nf=0;nf<4;++nf)
                acc[mf][nf] = __builtin_amdgcn_mfma_f32_16x16x32_f16(av[mf], bv[nf], acc[mf][nf], 0,0,0);
        __builtin_amdgcn_s_setprio(0);
        __syncthreads();
    }

    if (EPI == 0){
        #pragma unroll
        for (int mf=0;mf<4;++mf)
            #pragma unroll
            for (int nf=0;nf<4;++nf)
                #pragma unroll
                for (int j=0;j<4;++j)
                    Cf[(size_t)(m0+mf*16+lg*4+j)*D_MODEL + n0+nf*16+lr] = acc[mf][nf][j];
    } else {
        #pragma unroll
        for (int mf=0;mf<4;++mf){
            int r0 = m0 + mf*16 + lg*4;
            int b  = r0 >> 11, s = r0 & 2047;
            #pragma unroll
            for (int nf=0;nf<4;++nf){
                int col = n0 + nf*16 + lr;
                int which = col >> 10;
                int d  = col & 1023;
                int h  = d >> 6, di = d & 63;
                int bh = b*NHEAD + h;
                if (which == 2){
                    u16x4 pv;
                    pv.x = f2h_bits(acc[mf][nf][0]);
                    pv.y = f2h_bits(acc[mf][nf][1]);
                    pv.z = f2h_bits(acc[mf][nf][2]);
                    pv.w = f2h_bits(acc[mf][nf][3]);
                    *reinterpret_cast<u16x4*>(Vt + ((size_t)bh*HDIM + di)*S_LEN + s) = pv;
                } else {
                    u16* dst = (which==0 ? Qh : Kh) + ((size_t)bh*S_LEN + s)*HDIM + di;
                    #pragma unroll
                    for (int j=0;j<4;++j) dst[(size_t)j*HDIM] = f2h_bits(acc[mf][nf][j]);
                }
            }
        }
    }
}

// ---------- flash attention v5: QBLK=16, single-wave blocks, 4096 blocks ----------
// 32 bh x 128 q-tiles; heavy q-tiles first; bh = blk&31 -> XCD = blk%8 (K/V L2-pinned).
// Per-wave state ~half of QBLK=32 -> fits __launch_bounds__(64,4) (128-reg cap) with
// NO spills (round-5 lesson: spill traffic 201MB killed it). 16 waves/CU resident.
// Swapped QK^T softmax, exp2 domain, defer-rescale THR=8, early V issue — unchanged.
__global__ __launch_bounds__(64,4) void k_attn(const u16* __restrict__ Q, const u16* __restrict__ K,
                                               const u16* __restrict__ Vt, u16* __restrict__ Mg){
    __shared__ u16 plds[16][72];                 // 2304 B
    int lane = threadIdx.x;
    int lr = lane & 15, lg = lane >> 4;
    int blk = blockIdx.x;
    int bh  = blk & 31;
    int qt  = 127 - (blk >> 5);                  // heavy first
    int q0  = qt*16;
    int b = bh >> 4, h = bh & 15;
    const u16* Qp = Q  + (size_t)bh*S_LEN*HDIM;
    const u16* Kp = K  + (size_t)bh*S_LEN*HDIM;
    const u16* Vp = Vt + (size_t)bh*HDIM*S_LEN;

    // Q fragment (B-operand), 16 rows, pre-scaled by log2(e)
    half8 qf[2];
    #pragma unroll
    for (int ks=0;ks<2;++ks){
        half8 v = *reinterpret_cast<const half8*>(Qp + (size_t)(q0+lr)*HDIM + ks*32 + lg*8);
        #pragma unroll
        for (int j=0;j<8;++j) v[j] = v[j] * (_Float16)1.44269504f;
        qf[ks] = v;
    }

    f32x4 oacc[4];
    float mrow = -1e30f, lrow = 0.f;
    #pragma unroll
    for (int nf=0;nf<4;++nf) oacc[nf] = (f32x4){0.f,0.f,0.f,0.f};

    int ktiles = (q0 + 16 + 63) >> 6;            // 64-wide k tiles covering [0, q0+16)
    for (int kt=0; kt<ktiles; ++kt){
        int kbase = kt*64;
        // --- K fragments (A-operand) ---
        half8 kfr[4][2];
        #pragma unroll
        for (int kf=0;kf<4;++kf)
            #pragma unroll
            for (int ks=0;ks<2;++ks)
                kfr[kf][ks] = *reinterpret_cast<const half8*>(Kp + (size_t)(kbase+kf*16+lr)*HDIM + ks*32 + lg*8);
        // --- S^T = K Q^T : lane holds k = kf*16+lg*4+j, q = lr ---
        f32x4 sc[4];
        #pragma unroll
        for (int kf=0;kf<4;++kf) sc[kf] = (f32x4){0.f,0.f,0.f,0.f};
        __builtin_amdgcn_s_setprio(1);
        #pragma unroll
        for (int kf=0;kf<4;++kf)
            #pragma unroll
            for (int ks=0;ks<2;++ks)
                sc[kf] = __builtin_amdgcn_mfma_f32_16x16x32_f16(kfr[kf][ks], qf[ks], sc[kf], 0,0,0);
        __builtin_amdgcn_s_setprio(0);

        // --- V loads issued early: latency hides under softmax ---
        half8 vf[4][2];
        #pragma unroll
        for (int nf=0;nf<4;++nf)
            #pragma unroll
            for (int kh=0;kh<2;++kh)
                vf[nf][kh] = *reinterpret_cast<const half8*>(Vp + (size_t)(nf*16+lr)*S_LEN + kbase + kh*32 + lg*8);

        if (kt == ktiles-1){                     // causal mask on tail tile
            #pragma unroll
            for (int kf=0;kf<4;++kf)
                #pragma unroll
                for (int j=0;j<4;++j)
                    if (kbase+kf*16+lg*4+j > q0+lr) sc[kf][j] = -1e9f;
        }

        // --- row max: 15 in-reg + 2 shuffles ---
        float t0 = fmaxf(fmaxf(sc[0][0], sc[0][1]), fmaxf(sc[0][2], sc[0][3]));
        float t1 = fmaxf(fmaxf(sc[1][0], sc[1][1]), fmaxf(sc[1][2], sc[1][3]));
        float t2 = fmaxf(fmaxf(sc[2][0], sc[2][1]), fmaxf(sc[2][2], sc[2][3]));
        float t3 = fmaxf(fmaxf(sc[3][0], sc[3][1]), fmaxf(sc[3][2], sc[3][3]));
        float pmax = fmaxf(fmaxf(t0,t1), fmaxf(t2,t3));
        pmax = fmaxf(pmax, __shfl_xor(pmax,16));
        pmax = fmaxf(pmax, __shfl_xor(pmax,32));

        // --- defer-rescale (THR=8 in log2 domain -> P <= 256, fp16-safe) ---
        if (__any(pmax > mrow + 8.0f)){
            float mnew = fmaxf(mrow, pmax);
            float a = __builtin_amdgcn_exp2f(mrow - mnew);
            mrow = mnew;
            lrow *= a;
            float am[4];
            #pragma unroll
            for (int j=0;j<4;++j) am[j] = __shfl(a, lg*4+j);
            #pragma unroll
            for (int nf=0;nf<4;++nf)
                #pragma unroll
                for (int j=0;j<4;++j) oacc[nf][j] *= am[j];
        }
        // --- P = exp2(s - m), row sum in-register ---
        {
            float rs = 0.f;
            #pragma unroll
            for (int kf=0;kf<4;++kf)
                #pragma unroll
                for (int j=0;j<4;++j){
                    float e = __builtin_amdgcn_exp2f(sc[kf][j] - mrow);
                    sc[kf][j] = e;
                    rs += e;
                }
            rs += __shfl_xor(rs,16);
            rs += __shfl_xor(rs,32);
            lrow += rs;
        }
        // --- P -> LDS: k-contiguous j-regs pack to u16x4, 4x ds_write_b64 ---
        #pragma unroll
        for (int kf=0;kf<4;++kf){
            u16x4 pk;
            pk.x = f2h_bits(sc[kf][0]);
            pk.y = f2h_bits(sc[kf][1]);
            pk.z = f2h_bits(sc[kf][2]);
            pk.w = f2h_bits(sc[kf][3]);
            *reinterpret_cast<u16x4*>(&plds[lr][kf*16+lg*4]) = pk;
        }
        asm volatile("s_waitcnt lgkmcnt(0)" ::: "memory");
        __builtin_amdgcn_sched_barrier(0);

        half8 pa[2];
        #pragma unroll
        for (int kh=0;kh<2;++kh)
            pa[kh] = *reinterpret_cast<const half8*>(&plds[lr][kh*32 + lg*8]);
        __builtin_amdgcn_s_setprio(1);
        #pragma unroll
        for (int nf=0;nf<4;++nf)
            #pragma unroll
            for (int kh=0;kh<2;++kh)
                oacc[nf] = __builtin_amdgcn_mfma_f32_16x16x32_f16(pa[kh], vf[nf][kh], oacc[nf], 0,0,0);
        __builtin_amdgcn_s_setprio(0);
    }

    // epilogue: redistribute 1/l to oacc row layout (4 shuffles once)
    float linv[4];
    #pragma unroll
    for (int j=0;j<4;++j) linv[j] = 1.0f/__shfl(lrow, lg*4+j);
    #pragma unroll
    for (int nf=0;nf<4;++nf)
        #pragma unroll
        for (int j=0;j<4;++j)
            Mg[(size_t)(b*S_LEN + q0 + lg*4 + j)*D_MODEL + h*HDIM + nf*16 + lr]
                = f2h_bits(oacc[nf][j]*linv[j]);
}

extern "C" void kernel_launch(void* const* d_in, const int* in_sizes, int n_in,
                              void* d_out, int out_size, void* d_ws, size_t ws_size,
                              hipStream_t stream) {
    const float* x    = (const float*)d_in[0];
    const float* wqkv = (const float*)d_in[1];
    const float* wout = (const float*)d_in[2];
    float* out = (float*)d_out;
    char* ws = (char*)d_ws;

    const size_t MB = 1u<<20;
    u16* xh     = (u16*)(ws + 0*MB);
    u16* wqkvT  = (u16*)(ws + 8*MB);
    u16* woutT  = (u16*)(ws + 14*MB);
    u16* Qh     = (u16*)(ws + 16*MB);
    u16* Kh     = (u16*)(ws + 24*MB);
    u16* Vt     = (u16*)(ws + 32*MB);
    u16* Mg     = (u16*)(ws + 40*MB);

    k_cvt_x <<<4096, 256, 0, stream>>>(x, xh);
    k_cvt_wT<<<dim3(96,32), 256, 0, stream>>>(wqkv, wqkvT, 1024, 3072);
    k_cvt_wT<<<dim3(32,32), 256, 0, stream>>>(wout, woutT, 1024, 1024);
    k_gemm<1><<<768, 256, 0, stream>>>(xh, wqkvT, nullptr, Qh, Kh, Vt);
    k_attn  <<<4096, 64, 0, stream>>>(Qh, Kh, Vt, Mg);
    k_gemm<0><<<256, 256, 0, stream>>>(Mg, woutT, out, nullptr, nullptr, nullptr);
}

// Round 7
// 151.989 us; speedup vs baseline: 1.3411x; 1.3411x over previous
//
#include <hip/hip_runtime.h>
#include <stdint.h>

using u16 = unsigned short;
typedef __attribute__((ext_vector_type(8))) _Float16 half8;
typedef __attribute__((ext_vector_type(4))) float f32x4;
typedef __attribute__((ext_vector_type(4))) unsigned short u16x4;

#define S_LEN 2048
#define D_MODEL 1024
#define NHEAD 16
#define HDIM 64

__device__ __forceinline__ u16 f2h_bits(float f){
    _Float16 h = (_Float16)f;
    return __builtin_bit_cast(u16, h);
}

typedef __attribute__((address_space(1))) void gvoid;
typedef __attribute__((address_space(3))) void lvoid;
__device__ __forceinline__ void gload_lds16(const u16* g, u16* l){
    __builtin_amdgcn_global_load_lds((gvoid*)(uintptr_t)g, (lvoid*)l, 16, 0, 0);
}

// ---------- x fp32 -> fp16 ----------
__global__ __launch_bounds__(256) void k_cvt_x(const float* __restrict__ x, u16* __restrict__ xh){
    int i = blockIdx.x*256 + threadIdx.x;
    float4 v = reinterpret_cast<const float4*>(x)[i];
    u16x4 o;
    o.x = f2h_bits(v.x); o.y = f2h_bits(v.y); o.z = f2h_bits(v.z); o.w = f2h_bits(v.w);
    reinterpret_cast<u16x4*>(xh)[i] = o;
}

// ---------- W [K][N] fp32 -> WT [N][K] fp16 (transpose via LDS) ----------
__global__ __launch_bounds__(256) void k_cvt_wT(const float* __restrict__ W, u16* __restrict__ WT,
                                                int K, int N){
    __shared__ float t[32][33];
    int tx = threadIdx.x & 31, ty = threadIdx.x >> 5;   // 32 x 8
    int n0 = blockIdx.x*32, k0 = blockIdx.y*32;
    #pragma unroll
    for (int i=0;i<4;++i) t[ty+8*i][tx] = W[(size_t)(k0+ty+8*i)*N + n0+tx];
    __syncthreads();
    #pragma unroll
    for (int i=0;i<4;++i) WT[(size_t)(n0+ty+8*i)*K + k0+tx] = f2h_bits(t[tx][ty+8*i]);
}

// ---------- GEMM (m97 structure): 128x128 tile, BK=32, LDS-staged via global_load_lds ----------
template<int EPI>
__global__ __launch_bounds__(256) void k_gemm(const u16* __restrict__ A, const u16* __restrict__ BT,
                                              float* __restrict__ Cf, u16* __restrict__ Qh,
                                              u16* __restrict__ Kh, u16* __restrict__ Vt){
    constexpr int Kd = 1024;
    __shared__ u16 As[128*32];
    __shared__ u16 Bs[128*32];
    int nwg = gridDim.x;
    int cpx = nwg >> 3;
    int wg  = ((int)blockIdx.x & 7)*cpx + ((int)blockIdx.x >> 3);   // XCD-chunked
    int tm = wg & 31, tn = wg >> 5;                                 // m-fastest within chunk
    int t = threadIdx.x;
    int w = t >> 6, lane = t & 63;
    int lr = lane & 15, lg = lane >> 4;
    int wm = (w>>1)*64, wn = (w&1)*64;
    int m0 = tm*128 + wm, n0 = tn*128 + wn;

    const u16* aG = A  + (size_t)(tm*128 + (t>>2))*Kd + (t&3)*8;
    const u16* bG = BT + (size_t)(tn*128 + (t>>2))*Kd + (t&3)*8;
    u16* aL = As + (t>>2)*32 + (t&3)*8;
    u16* bL = Bs + (t>>2)*32 + (t&3)*8;

    f32x4 acc[4][4];
    #pragma unroll
    for (int i=0;i<4;++i)
        #pragma unroll
        for (int j=0;j<4;++j) acc[i][j] = (f32x4){0.f,0.f,0.f,0.f};

    for (int kk=0; kk<Kd; kk+=32){
        gload_lds16(aG + kk, aL);
        gload_lds16(aG + kk + (size_t)64*Kd, aL + 64*32);
        gload_lds16(bG + kk, bL);
        gload_lds16(bG + kk + (size_t)64*Kd, bL + 64*32);
        __syncthreads();

        half8 av[4], bv[4];
        #pragma unroll
        for (int mf=0;mf<4;++mf) av[mf] = *reinterpret_cast<const half8*>(&As[(wm+mf*16+lr)*32 + lg*8]);
        #pragma unroll
        for (int nf=0;nf<4;++nf) bv[nf] = *reinterpret_cast<const half8*>(&Bs[(wn+nf*16+lr)*32 + lg*8]);
        __builtin_amdgcn_s_setprio(1);
        #pragma unroll
        for (int mf=0;mf<4;++mf)
            #pragma unroll
            for (int nf=0;nf<4;++nf)
                acc[mf][nf] = __builtin_amdgcn_mfma_f32_16x16x32_f16(av[mf], bv[nf], acc[mf][nf], 0,0,0);
        __builtin_amdgcn_s_setprio(0);
        __syncthreads();
    }

    if (EPI == 0){
        #pragma unroll
        for (int mf=0;mf<4;++mf)
            #pragma unroll
            for (int nf=0;nf<4;++nf)
                #pragma unroll
                for (int j=0;j<4;++j)
                    Cf[(size_t)(m0+mf*16+lg*4+j)*D_MODEL + n0+nf*16+lr] = acc[mf][nf][j];
    } else {
        #pragma unroll
        for (int mf=0;mf<4;++mf){
            int r0 = m0 + mf*16 + lg*4;
            int b  = r0 >> 11, s = r0 & 2047;
            #pragma unroll
            for (int nf=0;nf<4;++nf){
                int col = n0 + nf*16 + lr;
                int which = col >> 10;
                int d  = col & 1023;
                int h  = d >> 6, di = d & 63;
                int bh = b*NHEAD + h;
                if (which == 2){
                    u16x4 pv;
                    pv.x = f2h_bits(acc[mf][nf][0]);
                    pv.y = f2h_bits(acc[mf][nf][1]);
                    pv.z = f2h_bits(acc[mf][nf][2]);
                    pv.w = f2h_bits(acc[mf][nf][3]);
                    *reinterpret_cast<u16x4*>(Vt + ((size_t)bh*HDIM + di)*S_LEN + s) = pv;
                } else {
                    u16* dst = (which==0 ? Qh : Kh) + ((size_t)bh*S_LEN + s)*HDIM + di;
                    #pragma unroll
                    for (int j=0;j<4;++j) dst[(size_t)j*HDIM] = f2h_bits(acc[mf][nf][j]);
                }
            }
        }
    }
}

// ---------- flash attention v6: QBLK=32, single-wave blocks, K register double-buffer ----------
// Round-6 diagnosis: VGPR starvation (52-80 regs) forced the compiler to serialize the
// 16 K/V loads per tile -> ~5600 cyc/tile of exposed L2 latency. Fix:
//  (a) __launch_bounds__(64,2): ~256-reg budget, 2 waves/SIMD.
//  (b) kA/kB register ping-pong: tile kt+1's 8 K loads issue at the TOP of tile kt's
//      body (static names, loop unrolled x2 - no dynamic indexing), in flight across
//      the whole ~1200-cyc compute. V loads unchanged (hide under softmax).
__global__ __launch_bounds__(64,2) void k_attn(const u16* __restrict__ Q, const u16* __restrict__ K,
                                               const u16* __restrict__ Vt, u16* __restrict__ Mg){
    __shared__ u16 plds[32][72];
    int lane = threadIdx.x;
    int lr = lane & 15, lg = lane >> 4;
    int blk = blockIdx.x;
    int bh  = blk & 31;                          // XCD = blk%8 clusters K/V in L2
    int qt  = 63 - (blk >> 5);                   // heavy q-tiles first
    int q0  = qt*32;
    int b = bh >> 4, h = bh & 15;
    const u16* Qp = Q  + (size_t)bh*S_LEN*HDIM;
    const u16* Kp = K  + (size_t)bh*S_LEN*HDIM;
    const u16* Vp = Vt + (size_t)bh*HDIM*S_LEN;

    // Q fragments (B-operand), pre-scaled by log2(e)
    half8 qf[2][2];
    #pragma unroll
    for (int qi=0;qi<2;++qi)
        #pragma unroll
        for (int ks=0;ks<2;++ks){
            half8 v = *reinterpret_cast<const half8*>(Qp + (size_t)(q0+qi*16+lr)*HDIM + ks*32 + lg*8);
            #pragma unroll
            for (int j=0;j<8;++j) v[j] = v[j] * (_Float16)1.44269504f;
            qf[qi][ks] = v;
        }

    f32x4 oacc[2][4];
    float mrow[2], lrow[2];
    #pragma unroll
    for (int mf=0;mf<2;++mf){
        #pragma unroll
        for (int nf=0;nf<4;++nf) oacc[mf][nf] = (f32x4){0.f,0.f,0.f,0.f};
        mrow[mf] = -1e30f; lrow[mf] = 0.f;
    }

    int ktiles = (q0 + 32 + 63) >> 6;

    half8 kA[4][2], kB[4][2];
    // prologue: K tile 0 -> kA
    #pragma unroll
    for (int kf=0;kf<4;++kf)
        #pragma unroll
        for (int ks=0;ks<2;++ks)
            kA[kf][ks] = *reinterpret_cast<const half8*>(Kp + (size_t)(kf*16+lr)*HDIM + ks*32 + lg*8);

    auto body = [&](half8 (&kc)[4][2], half8 (&kn)[4][2], int kt){
        int kbase = kt*64;
        // --- prefetch NEXT tile's K into the other buffer (in flight across this body) ---
        if (kt+1 < ktiles){
            int kbn = (kt+1)*64;
            #pragma unroll
            for (int kf=0;kf<4;++kf)
                #pragma unroll
                for (int ks=0;ks<2;++ks)
                    kn[kf][ks] = *reinterpret_cast<const half8*>(Kp + (size_t)(kbn+kf*16+lr)*HDIM + ks*32 + lg*8);
        }
        // --- S^T = K Q^T : lane holds k = kf*16+lg*4+j, q = qi*16+lr ---
        f32x4 sc[4][2];
        #pragma unroll
        for (int kf=0;kf<4;++kf)
            #pragma unroll
            for (int qi=0;qi<2;++qi) sc[kf][qi] = (f32x4){0.f,0.f,0.f,0.f};
        __builtin_amdgcn_s_setprio(1);
        #pragma unroll
        for (int kf=0;kf<4;++kf)
            #pragma unroll
            for (int qi=0;qi<2;++qi)
                #pragma unroll
                for (int ks=0;ks<2;++ks)
                    sc[kf][qi] = __builtin_amdgcn_mfma_f32_16x16x32_f16(kc[kf][ks], qf[qi][ks], sc[kf][qi], 0,0,0);
        __builtin_amdgcn_s_setprio(0);

        // --- V loads: latency hides under softmax ---
        half8 vf[4][2];
        #pragma unroll
        for (int nf=0;nf<4;++nf)
            #pragma unroll
            for (int kh=0;kh<2;++kh)
                vf[nf][kh] = *reinterpret_cast<const half8*>(Vp + (size_t)(nf*16+lr)*S_LEN + kbase + kh*32 + lg*8);

        if (kt == ktiles-1){                     // causal mask on tail tile
            #pragma unroll
            for (int kf=0;kf<4;++kf)
                #pragma unroll
                for (int qi=0;qi<2;++qi)
                    #pragma unroll
                    for (int j=0;j<4;++j)
                        if (kbase+kf*16+lg*4+j > q0+qi*16+lr) sc[kf][qi][j] = -1e9f;
        }

        // --- row max: in-reg + 2 shuffles per q-frag ---
        float pmax[2];
        #pragma unroll
        for (int qi=0;qi<2;++qi){
            float t0 = fmaxf(fmaxf(sc[0][qi][0], sc[0][qi][1]), fmaxf(sc[0][qi][2], sc[0][qi][3]));
            float t1 = fmaxf(fmaxf(sc[1][qi][0], sc[1][qi][1]), fmaxf(sc[1][qi][2], sc[1][qi][3]));
            float t2 = fmaxf(fmaxf(sc[2][qi][0], sc[2][qi][1]), fmaxf(sc[2][qi][2], sc[2][qi][3]));
            float t3 = fmaxf(fmaxf(sc[3][qi][0], sc[3][qi][1]), fmaxf(sc[3][qi][2], sc[3][qi][3]));
            float tm = fmaxf(fmaxf(t0,t1), fmaxf(t2,t3));
            tm = fmaxf(tm, __shfl_xor(tm,16));
            tm = fmaxf(tm, __shfl_xor(tm,32));
            pmax[qi] = tm;
        }
        // --- defer-rescale (THR=8 in log2 domain) ---
        bool need = (pmax[0] > mrow[0]+8.0f) || (pmax[1] > mrow[1]+8.0f);
        if (__any(need)){
            float aq[2];
            #pragma unroll
            for (int qi=0;qi<2;++qi){
                float mnew = fmaxf(mrow[qi], pmax[qi]);
                aq[qi] = __builtin_amdgcn_exp2f(mrow[qi] - mnew);
                mrow[qi] = mnew;
                lrow[qi] *= aq[qi];
            }
            float am[2][4];
            #pragma unroll
            for (int mf=0;mf<2;++mf)
                #pragma unroll
                for (int j=0;j<4;++j) am[mf][j] = __shfl(aq[mf], lg*4+j);
            #pragma unroll
            for (int mf=0;mf<2;++mf)
                #pragma unroll
                for (int nf=0;nf<4;++nf)
                    #pragma unroll
                    for (int j=0;j<4;++j) oacc[mf][nf][j] *= am[mf][j];
        }
        // --- P = exp2(s - m), row sum in-register ---
        #pragma unroll
        for (int qi=0;qi<2;++qi){
            float m = mrow[qi];
            float rs = 0.f;
            #pragma unroll
            for (int kf=0;kf<4;++kf)
                #pragma unroll
                for (int j=0;j<4;++j){
                    float e = __builtin_amdgcn_exp2f(sc[kf][qi][j] - m);
                    sc[kf][qi][j] = e;
                    rs += e;
                }
            rs += __shfl_xor(rs,16);
            rs += __shfl_xor(rs,32);
            lrow[qi] += rs;
        }
        // --- P -> LDS: k-contiguous j-regs pack to u16x4, 8x ds_write_b64 ---
        #pragma unroll
        for (int kf=0;kf<4;++kf)
            #pragma unroll
            for (int qi=0;qi<2;++qi){
                u16x4 pk;
                pk.x = f2h_bits(sc[kf][qi][0]);
                pk.y = f2h_bits(sc[kf][qi][1]);
                pk.z = f2h_bits(sc[kf][qi][2]);
                pk.w = f2h_bits(sc[kf][qi][3]);
                *reinterpret_cast<u16x4*>(&plds[qi*16+lr][kf*16+lg*4]) = pk;
            }
        asm volatile("s_waitcnt lgkmcnt(0)" ::: "memory");
        __builtin_amdgcn_sched_barrier(0);

        half8 pa[2][2];
        #pragma unroll
        for (int mf=0;mf<2;++mf)
            #pragma unroll
            for (int kh=0;kh<2;++kh)
                pa[mf][kh] = *reinterpret_cast<const half8*>(&plds[mf*16+lr][kh*32 + lg*8]);
        __builtin_amdgcn_s_setprio(1);
        #pragma unroll
        for (int mf=0;mf<2;++mf)
            #pragma unroll
            for (int nf=0;nf<4;++nf)
                #pragma unroll
                for (int kh=0;kh<2;++kh)
                    oacc[mf][nf] = __builtin_amdgcn_mfma_f32_16x16x32_f16(pa[mf][kh], vf[nf][kh], oacc[mf][nf], 0,0,0);
        __builtin_amdgcn_s_setprio(0);
    };

    int kt = 0;
    for (; kt+1 < ktiles; kt += 2){
        body(kA, kB, kt);
        body(kB, kA, kt+1);
    }
    if (kt < ktiles) body(kA, kB, kt);

    // epilogue: redistribute 1/l to oacc row layout
    float linv[2][4];
    #pragma unroll
    for (int mf=0;mf<2;++mf)
        #pragma unroll
        for (int j=0;j<4;++j) linv[mf][j] = 1.0f/__shfl(lrow[mf], lg*4+j);
    #pragma unroll
    for (int mf=0;mf<2;++mf)
        #pragma unroll
        for (int nf=0;nf<4;++nf)
            #pragma unroll
            for (int j=0;j<4;++j)
                Mg[(size_t)(b*S_LEN + q0 + mf*16 + lg*4 + j)*D_MODEL + h*HDIM + nf*16 + lr]
                    = f2h_bits(oacc[mf][nf][j]*linv[mf][j]);
}

extern "C" void kernel_launch(void* const* d_in, const int* in_sizes, int n_in,
                              void* d_out, int out_size, void* d_ws, size_t ws_size,
                              hipStream_t stream) {
    const float* x    = (const float*)d_in[0];
    const float* wqkv = (const float*)d_in[1];
    const float* wout = (const float*)d_in[2];
    float* out = (float*)d_out;
    char* ws = (char*)d_ws;

    const size_t MB = 1u<<20;
    u16* xh     = (u16*)(ws + 0*MB);
    u16* wqkvT  = (u16*)(ws + 8*MB);
    u16* woutT  = (u16*)(ws + 14*MB);
    u16* Qh     = (u16*)(ws + 16*MB);
    u16* Kh     = (u16*)(ws + 24*MB);
    u16* Vt     = (u16*)(ws + 32*MB);
    u16* Mg     = (u16*)(ws + 40*MB);

    k_cvt_x <<<4096, 256, 0, stream>>>(x, xh);
    k_cvt_wT<<<dim3(96,32), 256, 0, stream>>>(wqkv, wqkvT, 1024, 3072);
    k_cvt_wT<<<dim3(32,32), 256, 0, stream>>>(wout, woutT, 1024, 1024);
    k_gemm<1><<<768, 256, 0, stream>>>(xh, wqkvT, nullptr, Qh, Kh, Vt);
    k_attn  <<<2048, 64, 0, stream>>>(Qh, Kh, Vt, Mg);
    k_gemm<0><<<256, 256, 0, stream>>>(Mg, woutT, out, nullptr, nullptr, nullptr);
}